// Round 6
// baseline (569.064 us; speedup 1.0000x reference)
//
#include <hip/hip_runtime.h>

// Trilinear sparse-voxel upsampling, SCALE=2, R=128, C=32.
// fine = 2*c + o (o in {0,1}^3) => per-axis neighbors {c-1+o (w=0.25+0.5o), c+o (w=0.75-0.5o)}.
//
// Round-5 structure (2 voxels/wave, one probe instruction, sequential NT
// stores, short-lived blocks in input order) + COMPACTED LDS staging:
// only ~6 of 27 neighbor slots are occupied (19% grid), so valid rows are
// staged at rank-compacted slots (capacity 16 = 2 KiB/voxel instead of 4 KiB).
// LDS/block drops 32K->16K: occupancy goes 5 blocks (40 resident voxels/CU)
// -> 8 blocks/wave-cap (64 resident voxels/CU) = 1.6x memory-level parallelism.
// Session lessons baked in: input-order writes (r2), no persistent grids (r3),
// no extra serial probe level (r4). Overflow >16 valid rows (~1e-7/voxel,
// +5.5 sigma) falls back to direct global gather from live probe registers.

#define R 128
#define TABLE_ELEMS (R * R * R)
#define NSLOT 16                            // compact capacity per voxel

typedef float f32x4 __attribute__((ext_vector_type(4)));

__global__ void build_table_kernel(const int* __restrict__ coarse,
                                   int* __restrict__ table, int n) {
    int i = blockIdx.x * blockDim.x + threadIdx.x;
    if (i >= n) return;
    int x = coarse[i * 3 + 0];
    int y = coarse[i * 3 + 1];
    int z = coarse[i * 3 + 2];
    // numpy last-write-wins with increasing values == max row index
    atomicMax(&table[(x * R + y) * R + z], i);
}

__global__ void __launch_bounds__(256, 8)    // 8 waves/SIMD -> 8 blocks/CU
upsample_kernel(const f32x4* __restrict__ feat4,   // [n_in, 8] f32x4 == [n_in,32] f32
                const int* __restrict__ coarse,    // [n_in, 3]
                const int* __restrict__ table,     // [128^3] row index or -1
                f32x4* __restrict__ out4,          // [8*n_in, 8] f32x4
                int n_in) {
    __shared__ f32x4 sm[4][2][NSLOT * 8];          // 16 KiB per block

    int wib  = threadIdx.x >> 6;                   // wave within block
    int lane = threadIdx.x & 63;
    int half = lane >> 5;                          // 0: voxel A probes, 1: voxel B
    int pl   = lane & 31;                          // probe slot within half

    int viA = __builtin_amdgcn_readfirstlane(blockIdx.x * 8 + wib * 2);
    if (viA >= n_in) return;
    int viB = viA + 1;

    // ---- Phase 1: both voxels' 27-neighborhoods in ONE probe instruction ----
    int vi_p = half ? viB : viA;
    int myidx = -1;
    if (pl < 27 && vi_p < n_in) {
        int cx = coarse[vi_p * 3 + 0];
        int cy = coarse[vi_p * 3 + 1];
        int cz = coarse[vi_p * 3 + 2];
        int dx  = pl / 9;
        int rem = pl - dx * 9;
        int dy  = rem / 3;
        int dz  = rem - dy * 3;
        int x = cx + dx - 1, y = cy + dy - 1, z = cz + dz - 1;
        if ((unsigned)x < (unsigned)R && (unsigned)y < (unsigned)R &&
            (unsigned)z < (unsigned)R)
            myidx = table[(x * R + y) * R + z];
    }
    unsigned long long vmask = __ballot(myidx >= 0);
    unsigned maskA = (unsigned)(vmask & 0x7FFFFFFull);
    unsigned maskB = (unsigned)((vmask >> 32) & 0x7FFFFFFull);

    int g    = lane >> 3;                          // row-slot / child id
    int part = lane & 7;                           // which f32x4 of the 32-ch row

    // ---- Phase 2a: issue all feat loads to registers (one latency window) ----
    f32x4 fA0, fA1, fA2, fA3, fB0, fB1, fB2, fB3;
    {
        int i0 = __shfl(myidx, 0 * 8 + g);         // lanes 27-31 hold -1
        int i1 = __shfl(myidx, 1 * 8 + g);
        int i2 = __shfl(myidx, 2 * 8 + g);
        int i3 = __shfl(myidx, 3 * 8 + g);
        if (i0 >= 0) fA0 = feat4[(size_t)i0 * 8 + part];
        if (i1 >= 0) fA1 = feat4[(size_t)i1 * 8 + part];
        if (i2 >= 0) fA2 = feat4[(size_t)i2 * 8 + part];
        if (i3 >= 0) fA3 = feat4[(size_t)i3 * 8 + part];
        int j0 = __shfl(myidx, 32 + 0 * 8 + g);    // lanes 59-63 hold -1
        int j1 = __shfl(myidx, 32 + 1 * 8 + g);
        int j2 = __shfl(myidx, 32 + 2 * 8 + g);
        int j3 = __shfl(myidx, 32 + 3 * 8 + g);
        if (j0 >= 0) fB0 = feat4[(size_t)j0 * 8 + part];
        if (j1 >= 0) fB1 = feat4[(size_t)j1 * 8 + part];
        if (j2 >= 0) fB2 = feat4[(size_t)j2 * 8 + part];
        if (j3 >= 0) fB3 = feat4[(size_t)j3 * 8 + part];
    }

    // ---- Phase 2b: rank-compacted ds_writes (slot bit -> rank via popc) ----
    f32x4* smA = &sm[wib][0][0];
    f32x4* smB = &sm[wib][1][0];
#pragma unroll
    for (int r = 0; r < 4; ++r) {
        int s = r * 8 + g;                         // original slot 0..31
        unsigned bit = (s < 27) ? (1u << s) : 0u;
        if (maskA & bit) {
            int rk = __popc(maskA & (bit - 1u));
            if (rk < NSLOT) {
                f32x4 v = (r == 0) ? fA0 : (r == 1) ? fA1 : (r == 2) ? fA2 : fA3;
                smA[rk * 8 + part] = v;
            }
        }
        if (maskB & bit) {
            int rk = __popc(maskB & (bit - 1u));
            if (rk < NSLOT) {
                f32x4 v = (r == 0) ? fB0 : (r == 1) ? fB1 : (r == 2) ? fB2 : fB3;
                smB[rk * 8 + part] = v;
            }
        }
    }
    // wave-local producer->consumer: drain our own ds_writes before reading
    asm volatile("s_waitcnt lgkmcnt(0)" ::: "memory");
    __builtin_amdgcn_sched_barrier(0);

    // ---- Phase 3: child (g) x part: combine 8 corners from compacted LDS ----
    int ox = (g >> 2) & 1, oy = (g >> 1) & 1, oz = g & 1;
    float wx0 = 0.25f + 0.5f * (float)ox, wx1 = 0.75f - 0.5f * (float)ox;
    float wy0 = 0.25f + 0.5f * (float)oy, wy1 = 0.75f - 0.5f * (float)oy;
    float wz0 = 0.25f + 0.5f * (float)oz, wz1 = 0.75f - 0.5f * (float)oz;

    f32x4 accA = (f32x4)(0.f);
    f32x4 accB = (f32x4)(0.f);
#pragma unroll
    for (int k = 0; k < 8; ++k) {
        int kx = (k >> 2) & 1, ky = (k >> 1) & 1, kz = k & 1;
        int nb = (ox + kx) * 9 + (oy + ky) * 3 + (oz + kz);
        unsigned bit = 1u << nb;
        float w = (kx ? wx1 : wx0) * (ky ? wy1 : wy0) * (kz ? wz1 : wz0);
        if (maskA & bit) {
            int rk = __popc(maskA & (bit - 1u));
            f32x4 f;
            if (rk < NSLOT) f = smA[rk * 8 + part];
            else {                                  // ~1e-7/voxel overflow path
                int idx = __shfl(myidx, nb);
                f = feat4[(size_t)idx * 8 + part];
            }
            accA += w * f;
        }
        if (maskB & bit) {
            int rk = __popc(maskB & (bit - 1u));
            f32x4 f;
            if (rk < NSLOT) f = smB[rk * 8 + part];
            else {
                int idx = __shfl(myidx, 32 + nb);
                f = feat4[(size_t)idx * 8 + part];
            }
            accB += w * f;
        }
    }

    // out row m = vi*8 + child; element m*8 + part == vi*64 + lane
    // (2 KB of sequential NT stores per wave)
    __builtin_nontemporal_store(accA, &out4[(size_t)viA * 64 + lane]);
    if (viB < n_in)
        __builtin_nontemporal_store(accB, &out4[(size_t)viB * 64 + lane]);
}

extern "C" void kernel_launch(void* const* d_in, const int* in_sizes, int n_in_arrs,
                              void* d_out, int out_size, void* d_ws, size_t ws_size,
                              hipStream_t stream) {
    const float* feat = (const float*)d_in[0];
    const int* coarse = (const int*)d_in[1];
    // d_in[2] (fine_coords) is derivable from coarse_coords -- not read.

    int n_in = in_sizes[1] / 3;            // 400000
    int* table = (int*)d_ws;               // 8 MiB scratch

    hipMemsetAsync(table, 0xFF, (size_t)TABLE_ELEMS * sizeof(int), stream);

    build_table_kernel<<<(n_in + 255) / 256, 256, 0, stream>>>(coarse, table, n_in);

    int nblocks = (n_in + 7) / 8;          // 2 voxels per wave, 4 waves per block
    upsample_kernel<<<nblocks, 256, 0, stream>>>(
        (const f32x4*)feat, coarse, table, (f32x4*)d_out, n_in);
}